// Round 3
// baseline (155.210 us; speedup 1.0000x reference)
//
#include <hip/hip_runtime.h>

// exp(K), K = skew(theta) 64x64, scaling-and-squaring with MFMA.
//   A = K * 2^-5 ; T6(A) by Paterson-Stockmeyer (3 matmuls, antisymmetry
//   trick: B-operands read from ROW planes, result negated);
//   then 5 squarings tracking E = R - I:
//     (I+E)^2 = I + 2E + E^2 ; E kept in fp32 REGISTERS (linear term
//   exact), only E^2 goes through single-bf16 MFMA (8 MFMA/squaring).
// LDS: 4 planes x 8KB (stride 128B, XOR-swizzle (r&7)<<4) = 32KB
// -> 5 blocks/CU. One 256-thread block (2x2 waves, 32x32 tile each)
// per batch item.

typedef short s16x8 __attribute__((ext_vector_type(8)));
typedef float f32x4 __attribute__((ext_vector_type(4)));
typedef unsigned int u32;
typedef unsigned short u16;

#define NTH 2016
#define PL_STR 128       // plane row stride bytes (64 bf16)
#define OFF_A    0
#define OFF_A2   8192
#define OFF_A3   16384
#define OFF_P    24576
#define OFF_ER   0       // E row plane (overlays A; safe: A last read in mm2)
#define OFF_EC   8192    // E col plane (overlays A2; last read in mm2)
#define LDS_BYTES 32768

__device__ __forceinline__ u32 bf16_rne(float x) {
    u32 u = __builtin_bit_cast(u32, x);
    return (u + 0x7FFFu + ((u >> 16) & 1u)) >> 16;
}
__device__ __forceinline__ float bf2f(u32 h) {
    return __builtin_bit_cast(float, h << 16);
}
__device__ __forceinline__ s16x8 cast8(uint4 v) { return __builtin_bit_cast(s16x8, v); }

// swizzled byte offset within a plane: row r, byte-in-row bo
__device__ __forceinline__ int swz(int r, int bo) {
    return (r * PL_STR + bo) ^ ((r & 7) << 4);
}

__global__ __launch_bounds__(256, 5)
void so_expm_mfma2(const float* __restrict__ theta, float* __restrict__ out, int nbatch) {
    __shared__ __align__(16) char sm[LDS_BYTES];
    const int tid = threadIdx.x;
    const int b   = blockIdx.x;
    const int l   = tid & 63;
    const int wid = tid >> 6;
    const int wr = wid >> 1, wc = wid & 1;   // 2x2 wave grid
    const int q = l & 15, g = l >> 4;        // MFMA lane decomposition

    // ---- zero A plane (8192 B) ----
    {
        uint4* z = reinterpret_cast<uint4*>(sm + OFF_A);
        z[tid] = make_uint4(0, 0, 0, 0);
        z[tid + 256] = make_uint4(0, 0, 0, 0);
    }
    __syncthreads();

    // ---- scatter theta -> A = K * 2^-5 (bf16, swizzled plane) ----
    {
        const float* th = theta + (size_t)b * NTH;
        for (int t = tid; t < NTH; t += 256) {
            int i = (int)((127.0f - sqrtf(16129.0f - 8.0f * (float)t)) * 0.5f);
            if (i < 0) i = 0;
            if (i > 62) i = 62;
            while (i * (127 - i) / 2 > t) --i;
            while ((i + 1) * (127 - (i + 1)) / 2 <= t) ++i;
            const int j = i + 1 + (t - i * (127 - i) / 2);
            const float v = th[t] * 0.03125f;
            u32 hb = bf16_rne(v);
            *reinterpret_cast<u16*>(sm + OFF_A + swz(j, 2 * i)) = (u16)hb;             // +theta
            *reinterpret_cast<u16*>(sm + OFF_A + swz(i, 2 * j)) = (u16)(hb ^ 0x8000u); // -theta
        }
    }
    __syncthreads();

    const f32x4 zf = {0.f, 0.f, 0.f, 0.f};

    // matmul: acc[mt][nt] += Afrag(aoff rows) * Bfrag(boff rows, as B^T read)
    auto mmx = [&](int aoff, int boff, f32x4 acc[2][2]) {
        #pragma unroll
        for (int ks = 0; ks < 2; ++ks) {
            s16x8 af[2], bfr[2];
            #pragma unroll
            for (int mt = 0; mt < 2; ++mt) {
                int r = 32 * wr + 16 * mt + q;
                af[mt] = cast8(*reinterpret_cast<const uint4*>(sm + aoff + swz(r, 64 * ks + 16 * g)));
            }
            #pragma unroll
            for (int nt = 0; nt < 2; ++nt) {
                int n = 32 * wc + 16 * nt + q;
                bfr[nt] = cast8(*reinterpret_cast<const uint4*>(sm + boff + swz(n, 64 * ks + 16 * g)));
            }
            #pragma unroll
            for (int mt = 0; mt < 2; ++mt)
                #pragma unroll
                for (int nt = 0; nt < 2; ++nt)
                    acc[mt][nt] = __builtin_amdgcn_mfma_f32_16x16x32_bf16(
                        af[mt], bfr[nt], acc[mt][nt], 0, 0, 0);
        }
    };

    f32x4 acc[2][2];
    float areg[2][2][4], a2reg[2][2][4], ereg[2][2][4];

    // ---- mm1: acc = A*A^T = -A2 ; store A2 plane, keep areg/a2reg ----
    acc[0][0] = zf; acc[0][1] = zf; acc[1][0] = zf; acc[1][1] = zf;
    mmx(OFF_A, OFF_A, acc);
    #pragma unroll
    for (int mt = 0; mt < 2; ++mt)
        #pragma unroll
        for (int nt = 0; nt < 2; ++nt)
            #pragma unroll
            for (int e = 0; e < 4; ++e) {
                int r = 32 * wr + 16 * mt + 4 * g + e, c = 32 * wc + 16 * nt + q;
                areg[mt][nt][e] = bf2f(*reinterpret_cast<u16*>(sm + OFF_A + swz(r, 2 * c)));
                float v = -acc[mt][nt][e];
                a2reg[mt][nt][e] = v;
                *reinterpret_cast<u16*>(sm + OFF_A2 + swz(r, 2 * c)) = (u16)bf16_rne(v);
            }
    __syncthreads();

    // ---- mm2: acc = A2*A^T = -A3 ; store A3, P = I/6 + A/24 + A2/120 + A3/720 ----
    acc[0][0] = zf; acc[0][1] = zf; acc[1][0] = zf; acc[1][1] = zf;
    mmx(OFF_A2, OFF_A, acc);
    #pragma unroll
    for (int mt = 0; mt < 2; ++mt)
        #pragma unroll
        for (int nt = 0; nt < 2; ++nt)
            #pragma unroll
            for (int e = 0; e < 4; ++e) {
                int r = 32 * wr + 16 * mt + 4 * g + e, c = 32 * wc + 16 * nt + q;
                float x3 = -acc[mt][nt][e];
                *reinterpret_cast<u16*>(sm + OFF_A3 + swz(r, 2 * c)) = (u16)bf16_rne(x3);
                float pv = ((r == c) ? (1.f / 6.f) : 0.f)
                         + areg[mt][nt][e] * (1.f / 24.f)
                         + a2reg[mt][nt][e] * (1.f / 120.f)
                         + x3 * (1.f / 720.f);
                *reinterpret_cast<u16*>(sm + OFF_P + swz(r, 2 * c)) = (u16)bf16_rne(pv);
            }
    __syncthreads();

    // ---- mm3: acc = P*A3^T = -M ; E0 = A + A2/2 + M -> ereg + E planes ----
    acc[0][0] = zf; acc[0][1] = zf; acc[1][0] = zf; acc[1][1] = zf;
    mmx(OFF_P, OFF_A3, acc);
    // E planes overlay A/A2 which were last READ in mm2 (guarded by the sync
    // above); mm3 reads only P/A3, so writing ER/EC here is race-free.
    #pragma unroll
    for (int mt = 0; mt < 2; ++mt)
        #pragma unroll
        for (int nt = 0; nt < 2; ++nt) {
            u32 cb[4];
            #pragma unroll
            for (int e = 0; e < 4; ++e) {
                int r = 32 * wr + 16 * mt + 4 * g + e, c = 32 * wc + 16 * nt + q;
                float ev = areg[mt][nt][e] + 0.5f * a2reg[mt][nt][e] - acc[mt][nt][e];
                ereg[mt][nt][e] = ev;
                u32 hb = bf16_rne(ev);
                cb[e] = hb;
                *reinterpret_cast<u16*>(sm + OFF_ER + swz(r, 2 * c)) = (u16)hb;
            }
            // col plane: EC[c][r] = E[r][c]; lane's 4 rows are consecutive
            int r0 = 32 * wr + 16 * mt + 4 * g, c = 32 * wc + 16 * nt + q;
            uint2 v; v.x = cb[0] | (cb[1] << 16); v.y = cb[2] | (cb[3] << 16);
            *reinterpret_cast<uint2*>(sm + OFF_EC + swz(c, 2 * r0)) = v;
        }
    __syncthreads();

    // ---- 4 squarings in LDS: E <- 2E + E^2 ----
    #pragma unroll 1
    for (int sq = 0; sq < 4; ++sq) {
        acc[0][0] = zf; acc[0][1] = zf; acc[1][0] = zf; acc[1][1] = zf;
        mmx(OFF_ER, OFF_EC, acc);   // acc = E^2 (no negation)
        #pragma unroll
        for (int mt = 0; mt < 2; ++mt)
            #pragma unroll
            for (int nt = 0; nt < 2; ++nt)
                #pragma unroll
                for (int e = 0; e < 4; ++e)
                    ereg[mt][nt][e] = 2.f * ereg[mt][nt][e] + acc[mt][nt][e];
        __syncthreads();   // all reads of E planes done before overwrite
        #pragma unroll
        for (int mt = 0; mt < 2; ++mt)
            #pragma unroll
            for (int nt = 0; nt < 2; ++nt) {
                u32 cb[4];
                #pragma unroll
                for (int e = 0; e < 4; ++e) {
                    int r = 32 * wr + 16 * mt + 4 * g + e, c = 32 * wc + 16 * nt + q;
                    u32 hb = bf16_rne(ereg[mt][nt][e]);
                    cb[e] = hb;
                    *reinterpret_cast<u16*>(sm + OFF_ER + swz(r, 2 * c)) = (u16)hb;
                }
                int r0 = 32 * wr + 16 * mt + 4 * g, c = 32 * wc + 16 * nt + q;
                uint2 v; v.x = cb[0] | (cb[1] << 16); v.y = cb[2] | (cb[3] << 16);
                *reinterpret_cast<uint2*>(sm + OFF_EC + swz(c, 2 * r0)) = v;
            }
        __syncthreads();
    }

    // ---- 5th squaring straight to global: out = I + 2E + E^2 ----
    acc[0][0] = zf; acc[0][1] = zf; acc[1][0] = zf; acc[1][1] = zf;
    mmx(OFF_ER, OFF_EC, acc);
    float* op = out + (size_t)b * 4096;
    #pragma unroll
    for (int mt = 0; mt < 2; ++mt)
        #pragma unroll
        for (int nt = 0; nt < 2; ++nt)
            #pragma unroll
            for (int e = 0; e < 4; ++e) {
                int r = 32 * wr + 16 * mt + 4 * g + e, c = 32 * wc + 16 * nt + q;
                op[r * 64 + c] = ((r == c) ? 1.f : 0.f)
                               + 2.f * ereg[mt][nt][e] + acc[mt][nt][e];
            }
    (void)nbatch;
}

extern "C" void kernel_launch(void* const* d_in, const int* in_sizes, int n_in,
                              void* d_out, int out_size, void* d_ws, size_t ws_size,
                              hipStream_t stream) {
    const float* theta = (const float*)d_in[0];
    float* out = (float*)d_out;
    const int nbatch = in_sizes[0] / NTH;   // 8192
    so_expm_mfma2<<<nbatch, 256, 0, stream>>>(theta, out, nbatch);
}

// Round 4
// 93.127 us; speedup vs baseline: 1.6666x; 1.6666x over previous
//
#include <hip/hip_runtime.h>

// exp(K), K = skew(theta) 64x64, scaling-and-squaring with MFMA.
//   A = K * 2^-5 ; T6(A) by Paterson-Stockmeyer (3 matmuls, antisymmetry
//   trick: B-operands read from ROW planes, result negated);
//   then 5 squarings tracking E = R - I:
//     (I+E)^2 = I + 2E + E^2 ; E kept in fp32 REGISTERS (linear term
//   exact), only E^2 goes through single-bf16 MFMA (8 MFMA/squaring).
// LDS: 4 planes x 8KB (stride 128B, XOR-swizzle (r&7)<<4) = 32KB.
// launch_bounds(256,4): R3's (256,5) capped VGPRs at ~96 and spilled
// ereg/areg/a2reg to scratch (FETCH 190MB / WRITE 443MB vs 66/131 ideal)
// -- that spill traffic was the whole regression. 4 waves/EU gives a
// 128-VGPR budget; ~110 live regs fit with zero spill.

typedef short s16x8 __attribute__((ext_vector_type(8)));
typedef float f32x4 __attribute__((ext_vector_type(4)));
typedef unsigned int u32;
typedef unsigned short u16;

#define NTH 2016
#define PL_STR 128       // plane row stride bytes (64 bf16)
#define OFF_A    0
#define OFF_A2   8192
#define OFF_A3   16384
#define OFF_P    24576
#define OFF_ER   0       // E row plane (overlays A; safe: A last read in mm2)
#define OFF_EC   8192    // E col plane (overlays A2; last read in mm2)
#define LDS_BYTES 32768

__device__ __forceinline__ u32 bf16_rne(float x) {
    u32 u = __builtin_bit_cast(u32, x);
    return (u + 0x7FFFu + ((u >> 16) & 1u)) >> 16;
}
__device__ __forceinline__ float bf2f(u32 h) {
    return __builtin_bit_cast(float, h << 16);
}
__device__ __forceinline__ s16x8 cast8(uint4 v) { return __builtin_bit_cast(s16x8, v); }

// swizzled byte offset within a plane: row r, byte-in-row bo
__device__ __forceinline__ int swz(int r, int bo) {
    return (r * PL_STR + bo) ^ ((r & 7) << 4);
}

__global__ __launch_bounds__(256, 4)
void so_expm_mfma2(const float* __restrict__ theta, float* __restrict__ out, int nbatch) {
    __shared__ __align__(16) char sm[LDS_BYTES];
    const int tid = threadIdx.x;
    const int b   = blockIdx.x;
    const int l   = tid & 63;
    const int wid = tid >> 6;
    const int wr = wid >> 1, wc = wid & 1;   // 2x2 wave grid
    const int q = l & 15, g = l >> 4;        // MFMA lane decomposition

    // ---- zero A plane (8192 B) ----
    {
        uint4* z = reinterpret_cast<uint4*>(sm + OFF_A);
        z[tid] = make_uint4(0, 0, 0, 0);
        z[tid + 256] = make_uint4(0, 0, 0, 0);
    }
    __syncthreads();

    // ---- scatter theta -> A = K * 2^-5 (bf16, swizzled plane) ----
    {
        const float* th = theta + (size_t)b * NTH;
        for (int t = tid; t < NTH; t += 256) {
            int i = (int)((127.0f - sqrtf(16129.0f - 8.0f * (float)t)) * 0.5f);
            if (i < 0) i = 0;
            if (i > 62) i = 62;
            while (i * (127 - i) / 2 > t) --i;
            while ((i + 1) * (127 - (i + 1)) / 2 <= t) ++i;
            const int j = i + 1 + (t - i * (127 - i) / 2);
            const float v = th[t] * 0.03125f;
            u32 hb = bf16_rne(v);
            *reinterpret_cast<u16*>(sm + OFF_A + swz(j, 2 * i)) = (u16)hb;             // +theta
            *reinterpret_cast<u16*>(sm + OFF_A + swz(i, 2 * j)) = (u16)(hb ^ 0x8000u); // -theta
        }
    }
    __syncthreads();

    const f32x4 zf = {0.f, 0.f, 0.f, 0.f};

    // matmul: acc[mt][nt] += Afrag(aoff rows) * Bfrag(boff rows, as B^T read)
    auto mmx = [&](int aoff, int boff, f32x4 acc[2][2]) {
        #pragma unroll
        for (int ks = 0; ks < 2; ++ks) {
            s16x8 af[2], bfr[2];
            #pragma unroll
            for (int mt = 0; mt < 2; ++mt) {
                int r = 32 * wr + 16 * mt + q;
                af[mt] = cast8(*reinterpret_cast<const uint4*>(sm + aoff + swz(r, 64 * ks + 16 * g)));
            }
            #pragma unroll
            for (int nt = 0; nt < 2; ++nt) {
                int n = 32 * wc + 16 * nt + q;
                bfr[nt] = cast8(*reinterpret_cast<const uint4*>(sm + boff + swz(n, 64 * ks + 16 * g)));
            }
            #pragma unroll
            for (int mt = 0; mt < 2; ++mt)
                #pragma unroll
                for (int nt = 0; nt < 2; ++nt)
                    acc[mt][nt] = __builtin_amdgcn_mfma_f32_16x16x32_bf16(
                        af[mt], bfr[nt], acc[mt][nt], 0, 0, 0);
        }
    };

    f32x4 acc[2][2];
    float areg[2][2][4], a2reg[2][2][4], ereg[2][2][4];

    // ---- mm1: acc = A*A^T = -A2 ; store A2 plane, keep areg/a2reg ----
    acc[0][0] = zf; acc[0][1] = zf; acc[1][0] = zf; acc[1][1] = zf;
    mmx(OFF_A, OFF_A, acc);
    #pragma unroll
    for (int mt = 0; mt < 2; ++mt)
        #pragma unroll
        for (int nt = 0; nt < 2; ++nt)
            #pragma unroll
            for (int e = 0; e < 4; ++e) {
                int r = 32 * wr + 16 * mt + 4 * g + e, c = 32 * wc + 16 * nt + q;
                areg[mt][nt][e] = bf2f(*reinterpret_cast<u16*>(sm + OFF_A + swz(r, 2 * c)));
                float v = -acc[mt][nt][e];
                a2reg[mt][nt][e] = v;
                *reinterpret_cast<u16*>(sm + OFF_A2 + swz(r, 2 * c)) = (u16)bf16_rne(v);
            }
    __syncthreads();

    // ---- mm2: acc = A2*A^T = -A3 ; store A3, P = I/6 + A/24 + A2/120 + A3/720 ----
    acc[0][0] = zf; acc[0][1] = zf; acc[1][0] = zf; acc[1][1] = zf;
    mmx(OFF_A2, OFF_A, acc);
    #pragma unroll
    for (int mt = 0; mt < 2; ++mt)
        #pragma unroll
        for (int nt = 0; nt < 2; ++nt)
            #pragma unroll
            for (int e = 0; e < 4; ++e) {
                int r = 32 * wr + 16 * mt + 4 * g + e, c = 32 * wc + 16 * nt + q;
                float x3 = -acc[mt][nt][e];
                *reinterpret_cast<u16*>(sm + OFF_A3 + swz(r, 2 * c)) = (u16)bf16_rne(x3);
                float pv = ((r == c) ? (1.f / 6.f) : 0.f)
                         + areg[mt][nt][e] * (1.f / 24.f)
                         + a2reg[mt][nt][e] * (1.f / 120.f)
                         + x3 * (1.f / 720.f);
                *reinterpret_cast<u16*>(sm + OFF_P + swz(r, 2 * c)) = (u16)bf16_rne(pv);
            }
    __syncthreads();

    // ---- mm3: acc = P*A3^T = -M ; E0 = A + A2/2 + M -> ereg + E planes ----
    acc[0][0] = zf; acc[0][1] = zf; acc[1][0] = zf; acc[1][1] = zf;
    mmx(OFF_P, OFF_A3, acc);
    // E planes overlay A/A2 which were last READ in mm2 (guarded by the sync
    // above); mm3 reads only P/A3, so writing ER/EC here is race-free.
    #pragma unroll
    for (int mt = 0; mt < 2; ++mt)
        #pragma unroll
        for (int nt = 0; nt < 2; ++nt) {
            u32 cb[4];
            #pragma unroll
            for (int e = 0; e < 4; ++e) {
                int r = 32 * wr + 16 * mt + 4 * g + e, c = 32 * wc + 16 * nt + q;
                float ev = areg[mt][nt][e] + 0.5f * a2reg[mt][nt][e] - acc[mt][nt][e];
                ereg[mt][nt][e] = ev;
                u32 hb = bf16_rne(ev);
                cb[e] = hb;
                *reinterpret_cast<u16*>(sm + OFF_ER + swz(r, 2 * c)) = (u16)hb;
            }
            // col plane: EC[c][r] = E[r][c]; lane's 4 rows are consecutive
            int r0 = 32 * wr + 16 * mt + 4 * g, c = 32 * wc + 16 * nt + q;
            uint2 v; v.x = cb[0] | (cb[1] << 16); v.y = cb[2] | (cb[3] << 16);
            *reinterpret_cast<uint2*>(sm + OFF_EC + swz(c, 2 * r0)) = v;
        }
    __syncthreads();

    // ---- 4 squarings in LDS: E <- 2E + E^2 ----
    #pragma unroll 1
    for (int sq = 0; sq < 4; ++sq) {
        acc[0][0] = zf; acc[0][1] = zf; acc[1][0] = zf; acc[1][1] = zf;
        mmx(OFF_ER, OFF_EC, acc);   // acc = E^2 (no negation)
        #pragma unroll
        for (int mt = 0; mt < 2; ++mt)
            #pragma unroll
            for (int nt = 0; nt < 2; ++nt)
                #pragma unroll
                for (int e = 0; e < 4; ++e)
                    ereg[mt][nt][e] = 2.f * ereg[mt][nt][e] + acc[mt][nt][e];
        __syncthreads();   // all reads of E planes done before overwrite
        #pragma unroll
        for (int mt = 0; mt < 2; ++mt)
            #pragma unroll
            for (int nt = 0; nt < 2; ++nt) {
                u32 cb[4];
                #pragma unroll
                for (int e = 0; e < 4; ++e) {
                    int r = 32 * wr + 16 * mt + 4 * g + e, c = 32 * wc + 16 * nt + q;
                    u32 hb = bf16_rne(ereg[mt][nt][e]);
                    cb[e] = hb;
                    *reinterpret_cast<u16*>(sm + OFF_ER + swz(r, 2 * c)) = (u16)hb;
                }
                int r0 = 32 * wr + 16 * mt + 4 * g, c = 32 * wc + 16 * nt + q;
                uint2 v; v.x = cb[0] | (cb[1] << 16); v.y = cb[2] | (cb[3] << 16);
                *reinterpret_cast<uint2*>(sm + OFF_EC + swz(c, 2 * r0)) = v;
            }
        __syncthreads();
    }

    // ---- 5th squaring straight to global: out = I + 2E + E^2 ----
    acc[0][0] = zf; acc[0][1] = zf; acc[1][0] = zf; acc[1][1] = zf;
    mmx(OFF_ER, OFF_EC, acc);
    float* op = out + (size_t)b * 4096;
    #pragma unroll
    for (int mt = 0; mt < 2; ++mt)
        #pragma unroll
        for (int nt = 0; nt < 2; ++nt)
            #pragma unroll
            for (int e = 0; e < 4; ++e) {
                int r = 32 * wr + 16 * mt + 4 * g + e, c = 32 * wc + 16 * nt + q;
                op[r * 64 + c] = ((r == c) ? 1.f : 0.f)
                               + 2.f * ereg[mt][nt][e] + acc[mt][nt][e];
            }
    (void)nbatch;
}

extern "C" void kernel_launch(void* const* d_in, const int* in_sizes, int n_in,
                              void* d_out, int out_size, void* d_ws, size_t ws_size,
                              hipStream_t stream) {
    const float* theta = (const float*)d_in[0];
    float* out = (float*)d_out;
    const int nbatch = in_sizes[0] / NTH;   // 8192
    so_expm_mfma2<<<nbatch, 256, 0, stream>>>(theta, out, nbatch);
}

// Round 5
// 88.999 us; speedup vs baseline: 1.7440x; 1.0464x over previous
//
#include <hip/hip_runtime.h>

// exp(K), K = skew(theta) 64x64, scaling-and-squaring with MFMA.
//   A = K*2^-5 ; T6(A) Paterson-Stockmeyer; 5 squarings of E = R-I:
//   (I+E)^2 = I + 2E + E^2, E kept fp32 in regs (linear term exact),
//   E^2 via single-bf16 MFMA.
// DUAL-INTERP trick: with frags fwr (rows 32wr+16t+q of plane PA) and
// fwc (rows 32wc+16t+q of plane PB):
//   mfma(fwr[mt],fwc[nt]) = (PA*PB^T) in col-segment lane ownership
//   mfma(fwc[i], fwr[j])  = (PA*PB^T) in ROW-segment lane ownership
// Same 8 LDS frag reads serve both -> both ER (row) and EC (col) planes
// get contiguous uint2 writes (R4 needed 16 scattered b16 writes for ER).
// All f32->bf16 via v_cvt_pk_bf16_f32 (1 instr / 2 vals).
// LDS 32KB: A,A2 planes + ER,EC overlaying A3,P. launch_bounds(256,4).

typedef short s16x8 __attribute__((ext_vector_type(8)));
typedef float f32x4 __attribute__((ext_vector_type(4)));
typedef unsigned int u32;
typedef unsigned short u16;

#define NTH 2016
#define OFF_A    0
#define OFF_A2   8192
#define OFF_A3   16384
#define OFF_P    24576
#define OFF_ER   16384   // overlays A3 (dead after mm3 frag reads)
#define OFF_EC   24576   // overlays P
#define LDS_BYTES 32768

__device__ __forceinline__ u32 cvtpk(float a, float b) {  // lo=bf16(a), hi=bf16(b)
    u32 d;
    asm("v_cvt_pk_bf16_f32 %0, %1, %2" : "=v"(d) : "v"(a), "v"(b));
    return d;
}
__device__ __forceinline__ float bflo(u32 w) { return __builtin_bit_cast(float, w << 16); }
__device__ __forceinline__ float bfhi(u32 w) { return __builtin_bit_cast(float, w & 0xFFFF0000u); }
__device__ __forceinline__ float bf2f(u16 h) { return __builtin_bit_cast(float, (u32)h << 16); }
__device__ __forceinline__ s16x8 cast8(uint4 v) { return __builtin_bit_cast(s16x8, v); }
// swizzled byte offset: row r, byte-in-row bo (<128). XOR touches bits 4..6 only.
__device__ __forceinline__ int swz(int r, int bo) { return r * 128 + (bo ^ ((r & 7) << 4)); }

__global__ __launch_bounds__(256, 4)
void so_expm3(const float* __restrict__ theta, float* __restrict__ out) {
    __shared__ __align__(16) char sm[LDS_BYTES];
    const int tid = threadIdx.x;
    const int b   = blockIdx.x;
    const int l = tid & 63, wid = tid >> 6;
    const int wr = wid >> 1, wc = wid & 1;
    const int q = l & 15, g = l >> 4;

    // ---- scatter: thread owns row=tid>>2, 16 cols; forward triangular map ----
    {
        const int row = tid >> 2, cb = (tid & 3) * 16;
        const float* th = theta + (size_t)b * NTH;
        const int offr = row * (127 - row) / 2;
        float v[16];
        #pragma unroll
        for (int k = 0; k < 16; ++k) {
            const int c = cb + k;
            const int au = offr + c - row - 1;            // upper: t-index of (row,c)
            const int al = c * (127 - c) / 2 + row - c - 1; // lower: t-index of (c,row)
            const int idx = (c > row) ? au : ((c < row) ? al : 0);
            const float t = th[idx];
            v[k] = ((c > row) ? -t : ((c < row) ? t : 0.f)) * 0.03125f;
        }
        #pragma unroll
        for (int k = 0; k < 4; ++k) {
            uint2 u;
            u.x = cvtpk(v[4 * k + 0], v[4 * k + 1]);
            u.y = cvtpk(v[4 * k + 2], v[4 * k + 3]);
            *reinterpret_cast<uint2*>(sm + OFF_A + swz(row, 2 * cb + 8 * k)) = u;
        }
    }
    __syncthreads();

    // frag loader: f[t][ks] = 8 bf16 (k-consec) from plane rows (rbase+16t+q)
    auto ld2 = [&](int plane, int rbase, s16x8 f[2][2]) {
        #pragma unroll
        for (int t = 0; t < 2; ++t) {
            const int r = rbase + 16 * t + q;
            const int a0 = swz(r, 16 * g);
            f[t][0] = cast8(*reinterpret_cast<const uint4*>(sm + plane + a0));
            f[t][1] = cast8(*reinterpret_cast<const uint4*>(sm + plane + (a0 ^ 64)));
        }
    };
    // col-ownership: ac[mt][nt] = (PA*PB^T)[32wr+16mt+4g+e][32wc+16nt+q]
    auto mm_col = [&](s16x8 fwr[2][2], s16x8 fwc[2][2], f32x4 ac[2][2]) {
        #pragma unroll
        for (int ks = 0; ks < 2; ++ks)
            #pragma unroll
            for (int mt = 0; mt < 2; ++mt)
                #pragma unroll
                for (int nt = 0; nt < 2; ++nt)
                    ac[mt][nt] = __builtin_amdgcn_mfma_f32_16x16x32_bf16(
                        fwr[mt][ks], fwc[nt][ks], ac[mt][nt], 0, 0, 0);
    };
    // row-ownership: ar[j][i] = (PA*PB^T)[32wr+16j+q][32wc+16i+4g+e]
    auto mm_row = [&](s16x8 fwr[2][2], s16x8 fwc[2][2], f32x4 ar[2][2]) {
        #pragma unroll
        for (int ks = 0; ks < 2; ++ks)
            #pragma unroll
            for (int j = 0; j < 2; ++j)
                #pragma unroll
                for (int i = 0; i < 2; ++i)
                    ar[j][i] = __builtin_amdgcn_mfma_f32_16x16x32_bf16(
                        fwc[i][ks], fwr[j][ks], ar[j][i], 0, 0, 0);
    };

    const f32x4 zf = {0.f, 0.f, 0.f, 0.f};
    s16x8 fwr[2][2], fwc[2][2];
    f32x4 ar[2][2], ac[2][2];

    // ---- mm1: ar = A*A^T = -A2 (row-own) ; write A2 plane ----
    ar[0][0] = zf; ar[0][1] = zf; ar[1][0] = zf; ar[1][1] = zf;
    ld2(OFF_A, 32 * wr, fwr);
    ld2(OFF_A, 32 * wc, fwc);
    mm_row(fwr, fwc, ar);
    #pragma unroll
    for (int j = 0; j < 2; ++j)
        #pragma unroll
        for (int i = 0; i < 2; ++i) {
            const int r = 32 * wr + 16 * j + q, bo = 64 * wc + 32 * i + 8 * g;
            uint2 w;
            w.x = cvtpk(-ar[j][i][0], -ar[j][i][1]);
            w.y = cvtpk(-ar[j][i][2], -ar[j][i][3]);
            *reinterpret_cast<uint2*>(sm + OFF_A2 + swz(r, bo)) = w;
        }
    __syncthreads();

    // ---- mm2: ar = A2*A^T = -A3 (row-own) ; write A3 and P planes ----
    ar[0][0] = zf; ar[0][1] = zf; ar[1][0] = zf; ar[1][1] = zf;
    ld2(OFF_A2, 32 * wr, fwr);
    ld2(OFF_A, 32 * wc, fwc);
    mm_row(fwr, fwc, ar);
    #pragma unroll
    for (int j = 0; j < 2; ++j)
        #pragma unroll
        for (int i = 0; i < 2; ++i) {
            const int r = 32 * wr + 16 * j + q, bo = 64 * wc + 32 * i + 8 * g;
            const int c0 = 32 * wc + 16 * i + 4 * g;
            const uint2 ua  = *reinterpret_cast<const uint2*>(sm + OFF_A  + swz(r, bo));
            const uint2 ua2 = *reinterpret_cast<const uint2*>(sm + OFF_A2 + swz(r, bo));
            const float af[4]  = {bflo(ua.x),  bfhi(ua.x),  bflo(ua.y),  bfhi(ua.y)};
            const float a2f[4] = {bflo(ua2.x), bfhi(ua2.x), bflo(ua2.y), bfhi(ua2.y)};
            float a3v[4], pv[4];
            #pragma unroll
            for (int e = 0; e < 4; ++e) {
                a3v[e] = -ar[j][i][e];
                pv[e] = ((r == c0 + e) ? (1.f / 6.f) : 0.f)
                      + af[e] * (1.f / 24.f) + a2f[e] * (1.f / 120.f) + a3v[e] * (1.f / 720.f);
            }
            uint2 w3, wp;
            w3.x = cvtpk(a3v[0], a3v[1]); w3.y = cvtpk(a3v[2], a3v[3]);
            wp.x = cvtpk(pv[0], pv[1]);   wp.y = cvtpk(pv[2], pv[3]);
            *reinterpret_cast<uint2*>(sm + OFF_A3 + swz(r, bo)) = w3;
            *reinterpret_cast<uint2*>(sm + OFF_P  + swz(r, bo)) = wp;
        }
    __syncthreads();

    // ---- mm3: PA=P, PB=A3 -> -M both ownerships; E0 = A + A2/2 + M ----
    ar[0][0] = zf; ar[0][1] = zf; ar[1][0] = zf; ar[1][1] = zf;
    ac[0][0] = zf; ac[0][1] = zf; ac[1][0] = zf; ac[1][1] = zf;
    ld2(OFF_P, 32 * wr, fwr);
    ld2(OFF_A3, 32 * wc, fwc);
    mm_row(fwr, fwc, ar);
    mm_col(fwr, fwc, ac);
    float er_[2][2][4], ec_[2][2][4];
    // row state: positions [32wr+16j+q][32wc+16i+4g+e]
    #pragma unroll
    for (int j = 0; j < 2; ++j)
        #pragma unroll
        for (int i = 0; i < 2; ++i) {
            const int r = 32 * wr + 16 * j + q, bo = 64 * wc + 32 * i + 8 * g;
            const uint2 ua  = *reinterpret_cast<const uint2*>(sm + OFF_A  + swz(r, bo));
            const uint2 ua2 = *reinterpret_cast<const uint2*>(sm + OFF_A2 + swz(r, bo));
            const float af[4]  = {bflo(ua.x),  bfhi(ua.x),  bflo(ua.y),  bfhi(ua.y)};
            const float a2f[4] = {bflo(ua2.x), bfhi(ua2.x), bflo(ua2.y), bfhi(ua2.y)};
            #pragma unroll
            for (int e = 0; e < 4; ++e)
                er_[j][i][e] = af[e] + 0.5f * a2f[e] - ar[j][i][e];
        }
    // col state: positions [32wr+16mt+4g+e][32wc+16nt+q] (scattered b16 reads, once)
    #pragma unroll
    for (int mt = 0; mt < 2; ++mt)
        #pragma unroll
        for (int nt = 0; nt < 2; ++nt)
            #pragma unroll
            for (int e = 0; e < 4; ++e) {
                const int r = 32 * wr + 16 * mt + 4 * g + e;
                const int bo = 64 * wc + 32 * nt + 2 * q;
                const float af  = bf2f(*reinterpret_cast<const u16*>(sm + OFF_A  + swz(r, bo)));
                const float a2f = bf2f(*reinterpret_cast<const u16*>(sm + OFF_A2 + swz(r, bo)));
                ec_[mt][nt][e] = af + 0.5f * a2f - ac[mt][nt][e];
            }
    __syncthreads();   // all frag reads of A3/P done before ER/EC overlay
    #pragma unroll
    for (int j = 0; j < 2; ++j)
        #pragma unroll
        for (int i = 0; i < 2; ++i) {
            const int r = 32 * wr + 16 * j + q, bo = 64 * wc + 32 * i + 8 * g;
            uint2 w;
            w.x = cvtpk(er_[j][i][0], er_[j][i][1]);
            w.y = cvtpk(er_[j][i][2], er_[j][i][3]);
            *reinterpret_cast<uint2*>(sm + OFF_ER + swz(r, bo)) = w;
            const int rc = 32 * wc + 16 * i + q, boc = 64 * wr + 32 * j + 8 * g;
            uint2 wcv;
            wcv.x = cvtpk(ec_[j][i][0], ec_[j][i][1]);   // note: ec_ indexed [mt][nt]
            wcv.y = cvtpk(ec_[j][i][2], ec_[j][i][3]);
            *reinterpret_cast<uint2*>(sm + OFF_EC + swz(rc, boc)) = wcv;
        }
    __syncthreads();

    // ---- 4 squarings: E <- 2E + E^2, dual ownership, shared frags ----
    #pragma unroll 1
    for (int sq = 0; sq < 4; ++sq) {
        ar[0][0] = zf; ar[0][1] = zf; ar[1][0] = zf; ar[1][1] = zf;
        ac[0][0] = zf; ac[0][1] = zf; ac[1][0] = zf; ac[1][1] = zf;
        ld2(OFF_ER, 32 * wr, fwr);
        ld2(OFF_EC, 32 * wc, fwc);
        mm_row(fwr, fwc, ar);   // E^2 row-own  (ER*EC^T = E*E)
        mm_col(fwr, fwc, ac);   // E^2 col-own
        #pragma unroll
        for (int j = 0; j < 2; ++j)
            #pragma unroll
            for (int i = 0; i < 2; ++i)
                #pragma unroll
                for (int e = 0; e < 4; ++e) {
                    er_[j][i][e] = 2.f * er_[j][i][e] + ar[j][i][e];
                    ec_[j][i][e] = 2.f * ec_[j][i][e] + ac[j][i][e];
                }
        __syncthreads();
        #pragma unroll
        for (int j = 0; j < 2; ++j)
            #pragma unroll
            for (int i = 0; i < 2; ++i) {
                const int r = 32 * wr + 16 * j + q, bo = 64 * wc + 32 * i + 8 * g;
                uint2 w;
                w.x = cvtpk(er_[j][i][0], er_[j][i][1]);
                w.y = cvtpk(er_[j][i][2], er_[j][i][3]);
                *reinterpret_cast<uint2*>(sm + OFF_ER + swz(r, bo)) = w;
                const int rc = 32 * wc + 16 * i + q, boc = 64 * wr + 32 * j + 8 * g;
                uint2 wcv;
                wcv.x = cvtpk(ec_[j][i][0], ec_[j][i][1]);
                wcv.y = cvtpk(ec_[j][i][2], ec_[j][i][3]);
                *reinterpret_cast<uint2*>(sm + OFF_EC + swz(rc, boc)) = wcv;
            }
        __syncthreads();
    }

    // ---- 5th squaring: row-own only, straight to global (float4) ----
    ar[0][0] = zf; ar[0][1] = zf; ar[1][0] = zf; ar[1][1] = zf;
    ld2(OFF_ER, 32 * wr, fwr);
    ld2(OFF_EC, 32 * wc, fwc);
    mm_row(fwr, fwc, ar);
    float* op = out + (size_t)b * 4096;
    #pragma unroll
    for (int j = 0; j < 2; ++j)
        #pragma unroll
        for (int i = 0; i < 2; ++i) {
            const int r = 32 * wr + 16 * j + q, c0 = 32 * wc + 16 * i + 4 * g;
            float4 o;
            o.x = ((r == c0 + 0) ? 1.f : 0.f) + 2.f * er_[j][i][0] + ar[j][i][0];
            o.y = ((r == c0 + 1) ? 1.f : 0.f) + 2.f * er_[j][i][1] + ar[j][i][1];
            o.z = ((r == c0 + 2) ? 1.f : 0.f) + 2.f * er_[j][i][2] + ar[j][i][2];
            o.w = ((r == c0 + 3) ? 1.f : 0.f) + 2.f * er_[j][i][3] + ar[j][i][3];
            *reinterpret_cast<float4*>(op + r * 64 + c0) = o;
        }
}

extern "C" void kernel_launch(void* const* d_in, const int* in_sizes, int n_in,
                              void* d_out, int out_size, void* d_ws, size_t ws_size,
                              hipStream_t stream) {
    const float* theta = (const float*)d_in[0];
    float* out = (float*)d_out;
    const int nbatch = in_sizes[0] / NTH;   // 8192
    so_expm3<<<nbatch, 256, 0, stream>>>(theta, out);
}

// Round 6
// 68.532 us; speedup vs baseline: 2.2648x; 1.2986x over previous
//
#include <hip/hip_runtime.h>

// exp(K), K = skew(theta) 64x64.  R6: rebalanced scaling-and-squaring:
//   A = K * 2^-3 ;  T4(A) = I + A + A2/2 + A2*(A/6 + A2/24)  -- only 2
//   matmuls (B' = B^T = -A/6 + A2/24 stored so mm(A2,B') = A2*B = M);
//   then 3 squarings of E = R - I: (I+E)^2 = I + 2E + E^2, E fp32 in
//   regs (linear term exact), E^2 via single-bf16 MFMA.
// Error: truncation 0.24^5/120*8 ~ 5e-5; dominant error is bf16 rounding
// of final-squaring inputs (~2^-8), same as the 5-squaring scheme.
// DUAL-INTERP (verified R5): mfma(fwr[m],fwc[n]) = (PA*PB^T) col-own;
// mfma(fwc[i],fwr[j]) = (PA*PB^T) row-own -- same 8 frag reads serve
// both, so ER (row) and EC (col) planes get contiguous uint2 writes.
// LDS 24KB (3 planes; ER overlays B', EC overlays A2) -> 6 blocks/CU.

typedef short s16x8 __attribute__((ext_vector_type(8)));
typedef float f32x4 __attribute__((ext_vector_type(4)));
typedef unsigned int u32;
typedef unsigned short u16;

#define NTH 2016
#define OFF_A    0
#define OFF_A2   8192
#define OFF_B    16384
#define OFF_ER   16384   // overlays B' (dead after mm2 frag reads)
#define OFF_EC   8192    // overlays A2 (dead after mm2 epilogue reads)
#define LDS_BYTES 24576

__device__ __forceinline__ u32 cvtpk(float a, float b) {  // lo=bf16(a), hi=bf16(b)
    u32 d;
    asm("v_cvt_pk_bf16_f32 %0, %1, %2" : "=v"(d) : "v"(a), "v"(b));
    return d;
}
__device__ __forceinline__ float bflo(u32 w) { return __builtin_bit_cast(float, w << 16); }
__device__ __forceinline__ float bfhi(u32 w) { return __builtin_bit_cast(float, w & 0xFFFF0000u); }
__device__ __forceinline__ float bf2f(u16 h) { return __builtin_bit_cast(float, (u32)h << 16); }
__device__ __forceinline__ s16x8 cast8(uint4 v) { return __builtin_bit_cast(s16x8, v); }
// swizzled byte offset: row r, byte-in-row bo (<128). XOR touches bits 4..6 only.
__device__ __forceinline__ int swz(int r, int bo) { return r * 128 + (bo ^ ((r & 7) << 4)); }

__global__ __launch_bounds__(256, 4)
void so_expm4(const float* __restrict__ theta, float* __restrict__ out) {
    __shared__ __align__(16) char sm[LDS_BYTES];
    const int tid = threadIdx.x;
    const int b   = blockIdx.x;
    const int l = tid & 63, wid = tid >> 6;
    const int wr = wid >> 1, wc = wid & 1;
    const int q = l & 15, g = l >> 4;

    // ---- scatter: thread owns row=tid>>2, 16 cols; forward triangular map ----
    {
        const int row = tid >> 2, cb = (tid & 3) * 16;
        const float* th = theta + (size_t)b * NTH;
        const int offr = row * (127 - row) / 2;
        float v[16];
        #pragma unroll
        for (int k = 0; k < 16; ++k) {
            const int c = cb + k;
            const int au = offr + c - row - 1;              // upper: t-index of (row,c)
            const int al = c * (127 - c) / 2 + row - c - 1; // lower: t-index of (c,row)
            const int idx = (c > row) ? au : ((c < row) ? al : 0);
            const float t = th[idx];
            v[k] = ((c > row) ? -t : ((c < row) ? t : 0.f)) * 0.125f;   // A = K * 2^-3
        }
        #pragma unroll
        for (int k = 0; k < 4; ++k) {
            uint2 u;
            u.x = cvtpk(v[4 * k + 0], v[4 * k + 1]);
            u.y = cvtpk(v[4 * k + 2], v[4 * k + 3]);
            *reinterpret_cast<uint2*>(sm + OFF_A + swz(row, 2 * cb + 8 * k)) = u;
        }
    }
    __syncthreads();

    // frag loader: f[t][ks] = 8 bf16 (k-consec) from plane rows (rbase+16t+q)
    auto ld2 = [&](int plane, int rbase, s16x8 f[2][2]) {
        #pragma unroll
        for (int t = 0; t < 2; ++t) {
            const int r = rbase + 16 * t + q;
            const int a0 = swz(r, 16 * g);
            f[t][0] = cast8(*reinterpret_cast<const uint4*>(sm + plane + a0));
            f[t][1] = cast8(*reinterpret_cast<const uint4*>(sm + plane + (a0 ^ 64)));
        }
    };
    // col-ownership: ac[mt][nt] = (PA*PB^T)[32wr+16mt+4g+e][32wc+16nt+q]
    auto mm_col = [&](s16x8 fwr[2][2], s16x8 fwc[2][2], f32x4 ac[2][2]) {
        #pragma unroll
        for (int ks = 0; ks < 2; ++ks)
            #pragma unroll
            for (int mt = 0; mt < 2; ++mt)
                #pragma unroll
                for (int nt = 0; nt < 2; ++nt)
                    ac[mt][nt] = __builtin_amdgcn_mfma_f32_16x16x32_bf16(
                        fwr[mt][ks], fwc[nt][ks], ac[mt][nt], 0, 0, 0);
    };
    // row-ownership: ar[j][i] = (PA*PB^T)[32wr+16j+q][32wc+16i+4g+e]
    auto mm_row = [&](s16x8 fwr[2][2], s16x8 fwc[2][2], f32x4 ar[2][2]) {
        #pragma unroll
        for (int ks = 0; ks < 2; ++ks)
            #pragma unroll
            for (int j = 0; j < 2; ++j)
                #pragma unroll
                for (int i = 0; i < 2; ++i)
                    ar[j][i] = __builtin_amdgcn_mfma_f32_16x16x32_bf16(
                        fwc[i][ks], fwr[j][ks], ar[j][i], 0, 0, 0);
    };

    const f32x4 zf = {0.f, 0.f, 0.f, 0.f};
    s16x8 fwr[2][2], fwc[2][2];
    f32x4 ar[2][2], ac[2][2];

    // ---- mm1: ar = A*A^T = -A2 (row-own) ; write A2 and B' = -A/6 + A2/24 ----
    ar[0][0] = zf; ar[0][1] = zf; ar[1][0] = zf; ar[1][1] = zf;
    ld2(OFF_A, 32 * wr, fwr);
    ld2(OFF_A, 32 * wc, fwc);
    mm_row(fwr, fwc, ar);
    #pragma unroll
    for (int j = 0; j < 2; ++j)
        #pragma unroll
        for (int i = 0; i < 2; ++i) {
            const int r = 32 * wr + 16 * j + q, bo = 64 * wc + 32 * i + 8 * g;
            const uint2 ua = *reinterpret_cast<const uint2*>(sm + OFF_A + swz(r, bo));
            const float af[4] = {bflo(ua.x), bfhi(ua.x), bflo(ua.y), bfhi(ua.y)};
            float a2v[4], bv[4];
            #pragma unroll
            for (int e = 0; e < 4; ++e) {
                a2v[e] = -ar[j][i][e];
                bv[e]  = -af[e] * (1.f / 6.f) + a2v[e] * (1.f / 24.f);
            }
            uint2 w2, wb;
            w2.x = cvtpk(a2v[0], a2v[1]); w2.y = cvtpk(a2v[2], a2v[3]);
            wb.x = cvtpk(bv[0], bv[1]);   wb.y = cvtpk(bv[2], bv[3]);
            *reinterpret_cast<uint2*>(sm + OFF_A2 + swz(r, bo)) = w2;
            *reinterpret_cast<uint2*>(sm + OFF_B  + swz(r, bo)) = wb;
        }
    __syncthreads();

    // ---- mm2: M = A2*B'^T = A2*B (dual) ; E0 = A + A2/2 + M ----
    ar[0][0] = zf; ar[0][1] = zf; ar[1][0] = zf; ar[1][1] = zf;
    ac[0][0] = zf; ac[0][1] = zf; ac[1][0] = zf; ac[1][1] = zf;
    ld2(OFF_A2, 32 * wr, fwr);
    ld2(OFF_B, 32 * wc, fwc);
    mm_row(fwr, fwc, ar);
    mm_col(fwr, fwc, ac);
    float er_[2][2][4], ec_[2][2][4];
    // row state: positions [32wr+16j+q][32wc+16i+4g+e]
    #pragma unroll
    for (int j = 0; j < 2; ++j)
        #pragma unroll
        for (int i = 0; i < 2; ++i) {
            const int r = 32 * wr + 16 * j + q, bo = 64 * wc + 32 * i + 8 * g;
            const uint2 ua  = *reinterpret_cast<const uint2*>(sm + OFF_A  + swz(r, bo));
            const uint2 ua2 = *reinterpret_cast<const uint2*>(sm + OFF_A2 + swz(r, bo));
            const float af[4]  = {bflo(ua.x),  bfhi(ua.x),  bflo(ua.y),  bfhi(ua.y)};
            const float a2f[4] = {bflo(ua2.x), bfhi(ua2.x), bflo(ua2.y), bfhi(ua2.y)};
            #pragma unroll
            for (int e = 0; e < 4; ++e)
                er_[j][i][e] = af[e] + 0.5f * a2f[e] + ar[j][i][e];
        }
    // col state: positions [32wr+16mt+4g+e][32wc+16nt+q] (scattered b16 reads, once)
    #pragma unroll
    for (int mt = 0; mt < 2; ++mt)
        #pragma unroll
        for (int nt = 0; nt < 2; ++nt)
            #pragma unroll
            for (int e = 0; e < 4; ++e) {
                const int r = 32 * wr + 16 * mt + 4 * g + e;
                const int bo = 64 * wc + 32 * nt + 2 * q;
                const float af  = bf2f(*reinterpret_cast<const u16*>(sm + OFF_A  + swz(r, bo)));
                const float a2f = bf2f(*reinterpret_cast<const u16*>(sm + OFF_A2 + swz(r, bo)));
                ec_[mt][nt][e] = af + 0.5f * a2f + ac[mt][nt][e];
            }
    __syncthreads();   // frag reads of B' and epi reads of A2 done before overlay
    #pragma unroll
    for (int j = 0; j < 2; ++j)
        #pragma unroll
        for (int i = 0; i < 2; ++i) {
            const int r = 32 * wr + 16 * j + q, bo = 64 * wc + 32 * i + 8 * g;
            uint2 w;
            w.x = cvtpk(er_[j][i][0], er_[j][i][1]);
            w.y = cvtpk(er_[j][i][2], er_[j][i][3]);
            *reinterpret_cast<uint2*>(sm + OFF_ER + swz(r, bo)) = w;
            const int rc = 32 * wc + 16 * i + q, boc = 64 * wr + 32 * j + 8 * g;
            uint2 wcv;
            wcv.x = cvtpk(ec_[j][i][0], ec_[j][i][1]);   // ec_ indexed [mt][nt]
            wcv.y = cvtpk(ec_[j][i][2], ec_[j][i][3]);
            *reinterpret_cast<uint2*>(sm + OFF_EC + swz(rc, boc)) = wcv;
        }
    __syncthreads();

    // ---- 2 squarings: E <- 2E + E^2, dual ownership, shared frags ----
    #pragma unroll 1
    for (int sq = 0; sq < 2; ++sq) {
        ar[0][0] = zf; ar[0][1] = zf; ar[1][0] = zf; ar[1][1] = zf;
        ac[0][0] = zf; ac[0][1] = zf; ac[1][0] = zf; ac[1][1] = zf;
        ld2(OFF_ER, 32 * wr, fwr);
        ld2(OFF_EC, 32 * wc, fwc);
        mm_row(fwr, fwc, ar);   // E^2 row-own  (ER*EC^T = E*E)
        mm_col(fwr, fwc, ac);   // E^2 col-own
        #pragma unroll
        for (int j = 0; j < 2; ++j)
            #pragma unroll
            for (int i = 0; i < 2; ++i)
                #pragma unroll
                for (int e = 0; e < 4; ++e) {
                    er_[j][i][e] = 2.f * er_[j][i][e] + ar[j][i][e];
                    ec_[j][i][e] = 2.f * ec_[j][i][e] + ac[j][i][e];
                }
        __syncthreads();
        #pragma unroll
        for (int j = 0; j < 2; ++j)
            #pragma unroll
            for (int i = 0; i < 2; ++i) {
                const int r = 32 * wr + 16 * j + q, bo = 64 * wc + 32 * i + 8 * g;
                uint2 w;
                w.x = cvtpk(er_[j][i][0], er_[j][i][1]);
                w.y = cvtpk(er_[j][i][2], er_[j][i][3]);
                *reinterpret_cast<uint2*>(sm + OFF_ER + swz(r, bo)) = w;
                const int rc = 32 * wc + 16 * i + q, boc = 64 * wr + 32 * j + 8 * g;
                uint2 wcv;
                wcv.x = cvtpk(ec_[j][i][0], ec_[j][i][1]);
                wcv.y = cvtpk(ec_[j][i][2], ec_[j][i][3]);
                *reinterpret_cast<uint2*>(sm + OFF_EC + swz(rc, boc)) = wcv;
            }
        __syncthreads();
    }

    // ---- 3rd squaring: row-own only, straight to global (float4) ----
    ar[0][0] = zf; ar[0][1] = zf; ar[1][0] = zf; ar[1][1] = zf;
    ld2(OFF_ER, 32 * wr, fwr);
    ld2(OFF_EC, 32 * wc, fwc);
    mm_row(fwr, fwc, ar);
    float* op = out + (size_t)b * 4096;
    #pragma unroll
    for (int j = 0; j < 2; ++j)
        #pragma unroll
        for (int i = 0; i < 2; ++i) {
            const int r = 32 * wr + 16 * j + q, c0 = 32 * wc + 16 * i + 4 * g;
            float4 o;
            o.x = ((r == c0 + 0) ? 1.f : 0.f) + 2.f * er_[j][i][0] + ar[j][i][0];
            o.y = ((r == c0 + 1) ? 1.f : 0.f) + 2.f * er_[j][i][1] + ar[j][i][1];
            o.z = ((r == c0 + 2) ? 1.f : 0.f) + 2.f * er_[j][i][2] + ar[j][i][2];
            o.w = ((r == c0 + 3) ? 1.f : 0.f) + 2.f * er_[j][i][3] + ar[j][i][3];
            *reinterpret_cast<float4*>(op + r * 64 + c0) = o;
        }
}

extern "C" void kernel_launch(void* const* d_in, const int* in_sizes, int n_in,
                              void* d_out, int out_size, void* d_ws, size_t ws_size,
                              hipStream_t stream) {
    const float* theta = (const float*)d_in[0];
    float* out = (float*)d_out;
    const int nbatch = in_sizes[0] / NTH;   // 8192
    so_expm4<<<nbatch, 256, 0, stream>>>(theta, out);
}